// Round 5
// baseline (61.768 us; speedup 1.0000x reference)
//
#include <hip/hip_runtime.h>
#include <hip/hip_bf16.h>
#include <math.h>

#define TAU 0.75f

typedef _Float16 half8 __attribute__((ext_vector_type(8)));
typedef float    f32x4 __attribute__((ext_vector_type(4)));

// ws layout (float offsets)
#define WS_REP   0      // rep[64][64]
#define WS_NORM2 4096   // base ||W||^2
#define WS_FSC   4100   // f scale [128]
#define WS_BADD  4228   // f*bias*b [128]
#define WS_WF16  4360   // f16 fused conv weights [3][128][64] (16B-aligned)

// ---------------------------------------------------------------------------
// K1: blocks 0..255 -> (chunk c = b>>2, h-quarter hq = b&3): rep[c][hq*16..+15].
//     block 256     -> base Frobenius norm^2 of W.
// ---------------------------------------------------------------------------
__global__ __launch_bounds__(256) void k1_rep(
    const float* __restrict__ grads, const float* __restrict__ ctrl_w,
    const float* __restrict__ ctrl_b, const float* __restrict__ W,
    float* __restrict__ ws)
{
    const int t = threadIdx.x;
    if (blockIdx.x == 256) {
        __shared__ float red[256];
        float ss = 0.f;
        for (int e = t; e < 3584; e += 256) {
            const float4 w4 = ((const float4*)W)[e];
            ss += w4.x * w4.x + w4.y * w4.y + w4.z * w4.z + w4.w * w4.w;
        }
        red[t] = ss; __syncthreads();
        for (int s = 128; s > 0; s >>= 1) { if (t < s) red[t] += red[t + s]; __syncthreads(); }
        if (t == 0) ws[WS_NORM2] = red[0];
        return;
    }
    const int c = blockIdx.x >> 2, hq = blockIdx.x & 3;
    __shared__ float gS[384];
    if (t < 96) ((float4*)gS)[t] = ((const float4*)(grads + c * 384))[t];
    __syncthreads();
    const int hl = t >> 4, sub = t & 15;
    const int h = hq * 16 + hl;
    const float4* wa = (const float4*)(ctrl_w + h * 384) + sub * 6;
    const float4* ga = (const float4*)gS + sub * 6;
    float dot = 0.f;
    #pragma unroll
    for (int d = 0; d < 6; d++) {
        const float4 a = ga[d], b = wa[d];
        dot += a.x * b.x + a.y * b.y + a.z * b.z + a.w * b.w;
    }
    dot += __shfl_xor(dot, 1); dot += __shfl_xor(dot, 2);
    dot += __shfl_xor(dot, 4); dot += __shfl_xor(dot, 8);
    if (sub == 0) {
        const float z = dot + ctrl_b[h];
        ws[WS_REP + c * 64 + h] = z / (1.f + expf(-z));
    }
}

// ---------------------------------------------------------------------------
// K23: each of 152 blocks redundantly computes q -> scores -> softmax -> top2
// -> old_w -> norm correction (identical/deterministic in every block), then
// writes its 256-element slice of {W_out, wf}. Block 0 also writes fsc/badd.
// ---------------------------------------------------------------------------
__global__ __launch_bounds__(256) void k23(
    const float* __restrict__ W, const float* __restrict__ bias_param,
    const float* __restrict__ conv_weight,
    const float* __restrict__ cw_w, const float* __restrict__ cw_b,
    const float* __restrict__ cb_w, const float* __restrict__ cb_b,
    const float* __restrict__ cf_w, const float* __restrict__ cf_b,
    const int* __restrict__ trigger, float* __restrict__ ws,
    float* __restrict__ W_out, _Float16* __restrict__ wf_out)
{
    __shared__ float repS[4096];
    __shared__ float qS[448], owS[448], wqS[192], sS[32], red[256];
    __shared__ int   idxS[2];
    __shared__ float vS[2], scaleS;

    const int t = threadIdx.x;
    const int trig = trigger[0];

    for (int e = t; e < 1024; e += 256)
        ((float4*)repS)[e] = ((const float4*)(ws + WS_REP))[e];
    __syncthreads();

    for (int e = t; e < 448; e += 256) {
        const float* wv; float bias; int c;
        if (e < 192)      { c = e / 3;              const int j = e - c * 3; wv = cw_w + j * 64; bias = cw_b[j]; }
        else if (e < 320) { const int e2 = e - 192; c = e2 >> 1; const int j = e2 & 1; wv = cb_w + j * 64; bias = cb_b[j]; }
        else              { const int e2 = e - 320; c = e2 >> 1; const int j = e2 & 1; wv = cf_w + j * 64; bias = cf_b[j]; }
        const float* rr = repS + c * 64;
        float dot = 0.f;
        #pragma unroll 8
        for (int h = 0; h < 64; h++) dot += rr[h] * wv[h];
        qS[e] = dot + bias;
    }
    __syncthreads();

    {
        const int m = t >> 3, sub = t & 7;
        float s = 0.f;
        for (int d = sub; d < 448; d += 8) s += qS[d] * W[d * 32 + m];
        s += __shfl_xor(s, 1); s += __shfl_xor(s, 2); s += __shfl_xor(s, 4);
        if (sub == 0) sS[m] = 2.f * s;
    }
    __syncthreads();
    if (t == 0) {
        float mx = sS[0];
        for (int m = 1; m < 32; m++) mx = fmaxf(mx, sS[m]);
        float sum = 0.f; float att[32];
        for (int m = 0; m < 32; m++) { att[m] = expf(sS[m] - mx); sum += att[m]; }
        const float inv = 1.f / sum;
        int i0 = 0; float v0 = att[0];
        for (int m = 1; m < 32; m++) if (att[m] > v0) { v0 = att[m]; i0 = m; }
        int i1 = -1; float v1 = -1.f;
        for (int m = 0; m < 32; m++) { if (m == i0) continue; if (att[m] > v1) { v1 = att[m]; i1 = m; } }
        idxS[0] = i0; idxS[1] = i1; vS[0] = v0 * inv; vS[1] = v1 * inv;
    }
    __syncthreads();
    const int i0 = idxS[0], i1 = idxS[1];
    const float v0 = vS[0], v1 = vS[1];

    for (int d = t; d < 448; d += 256)
        owS[d] = (trig == 1) ? (W[d * 32 + i0] * (float)i0 + W[d * 32 + i1] * (float)i1) : 0.f;
    __syncthreads();

    float corr = 0.f;
    if (trig == 1) {
        for (int d = t; d < 448; d += 256) {
            const float w0 = W[d * 32 + i0], w1 = W[d * 32 + i1];
            const float n0 = TAU * w0 + 0.25f * owS[d] * v0;
            const float n1 = TAU * w1 + 0.25f * owS[d] * v1;
            corr += n0 * n0 - w0 * w0 + n1 * n1 - w1 * w1;
        }
    }
    red[t] = corr; __syncthreads();
    for (int s = 128; s > 0; s >>= 1) { if (t < s) red[t] += red[t + s]; __syncthreads(); }
    if (t == 0) {
        float n = sqrtf(fmaxf(ws[WS_NORM2] + red[0], 0.f));
        scaleS = 1.f / fmaxf(n, 1.f);
    }
    if (t < 192) wqS[t] = (trig == 1) ? (TAU * qS[t] + 0.25f * owS[t]) : qS[t];
    __syncthreads();

    if (blockIdx.x == 0 && t < 128) {
        float bb = qS[192 + t], ff = qS[320 + t];
        if (trig == 1) {
            bb = TAU * bb + 0.25f * owS[192 + t];
            ff = TAU * ff + 0.25f * owS[320 + t];
        }
        ws[WS_FSC + t]  = ff;
        ws[WS_BADD + t] = ff * bias_param[t] * bb;
    }

    const int g = blockIdx.x * 256 + t;
    if (g < 14336) {
        const float wv = W[g];
        float wn = wv;
        if (trig == 1) {
            const int d = g >> 5, m = g & 31;
            if (m == i0)      wn = TAU * wv + 0.25f * owS[d] * v0;
            else if (m == i1) wn = TAU * wv + 0.25f * owS[d] * v1;
            wn *= scaleS;
        }
        W_out[g] = wn;
    } else {
        const int e2 = g - 14336;            // (o*64+i)*3+kk
        const int o   = e2 / 192;
        const int rem = e2 - o * 192;
        const int i   = rem / 3;
        const int kk  = rem - i * 3;
        wf_out[(kk * 128 + o) * 64 + i] = (_Float16)(conv_weight[e2] * wqS[rem]);
    }
}

// ---------------------------------------------------------------------------
// Conv via f16 MFMA. Block: 128 o x 64 l, 4 waves x (32o,64l).
// Grid: 32 b * 64 l-tiles = 2048 blocks (~8/CU queued -> two overlapping
// generations per CU: gen2 reads overlap gen1 store-drain).
// ---------------------------------------------------------------------------
__global__ __launch_bounds__(256, 5) void conv_mfma(
    const float* __restrict__ x, const _Float16* __restrict__ wf,
    const float* __restrict__ fsc, const float* __restrict__ badd,
    float* __restrict__ out)
{
    __shared__ __align__(16) _Float16 xs[66 * 72];

    const int t    = threadIdx.x;
    const int wv   = t >> 6;
    const int lane = t & 63;
    const int lrow = lane & 15;
    const int lgrp = lane >> 4;
    const int b    = blockIdx.x >> 6;
    const int l0   = (blockIdx.x & 63) * 64;
    const int obase = wv * 32;

    const float* xb = x + (size_t)b * 64 * 4096;
    const int ci = t & 3;          // l-chunk of 16
    const int ir = t >> 2;         // row i, 0..63

    // edge values (c=0 -> l0-1, c=65 -> l0+64)
    float xe = 0.f;
    const int ei = t & 63, side = t >> 6;
    if (t < 128) {
        const int l = side ? (l0 + 64) : (l0 - 1);
        xe = (l >= 0 && l < 4096) ? xb[(size_t)ei * 4096 + l] : 0.f;
    }

    // A fragments: wf[kk][o][i]
    half8 A[2][2][3];
    #pragma unroll
    for (int of = 0; of < 2; of++)
        #pragma unroll
        for (int ch = 0; ch < 2; ch++)
            #pragma unroll
            for (int kk = 0; kk < 3; kk++)
                A[of][ch][kk] = *(const half8*)(wf + ((kk * 128 + obase + of * 16 + lrow) * 64 + ch * 32 + lgrp * 8));

    // stage x -> xs[c][i] transposed; coalesced reads (16 rows x 64B / instr)
    {
        float4 xr[4];
        #pragma unroll
        for (int j = 0; j < 4; j++)
            xr[j] = *(const float4*)(xb + (size_t)ir * 4096 + l0 + ci * 16 + j * 4);
        #pragma unroll
        for (int j = 0; j < 4; j++) {
            _Float16* p = xs + (ci * 16 + j * 4 + 1) * 72 + ir;
            p[0]   = (_Float16)xr[j].x;
            p[72]  = (_Float16)xr[j].y;
            p[144] = (_Float16)xr[j].z;
            p[216] = (_Float16)xr[j].w;
        }
    }
    if (t < 128) xs[(side ? 65 : 0) * 72 + ei] = (_Float16)xe;

    f32x4 acc[2][4];
    #pragma unroll
    for (int of = 0; of < 2; of++)
        #pragma unroll
        for (int lf = 0; lf < 4; lf++) acc[of][lf] = (f32x4)0.f;

    __syncthreads();

    #pragma unroll
    for (int ch = 0; ch < 2; ch++) {
        #pragma unroll
        for (int kk = 0; kk < 3; kk++) {
            half8 B[4];
            #pragma unroll
            for (int lf = 0; lf < 4; lf++)
                B[lf] = *(const half8*)(xs + (lf * 16 + lrow + kk) * 72 + ch * 32 + lgrp * 8);
            #pragma unroll
            for (int of = 0; of < 2; of++)
                #pragma unroll
                for (int lf = 0; lf < 4; lf++)
                    acc[of][lf] = __builtin_amdgcn_mfma_f32_16x16x32_f16(A[of][ch][kk], B[lf], acc[of][lf], 0, 0, 0);
        }
    }

    // epilogue: o = obase + of*16 + lgrp*4 + r ; l = l0 + lf*16 + lrow
    #pragma unroll
    for (int of = 0; of < 2; of++) {
        const int ob = obase + of * 16 + lgrp * 4;
        float fs[4], ba[4];
        #pragma unroll
        for (int r = 0; r < 4; r++) { fs[r] = fsc[ob + r]; ba[r] = badd[ob + r]; }
        #pragma unroll
        for (int lf = 0; lf < 4; lf++) {
            const int l = l0 + lf * 16 + lrow;
            float* op = out + ((size_t)(b * 128 + ob)) * 4096 + l;
            #pragma unroll
            for (int r = 0; r < 4; r++)
                op[(size_t)r * 4096] = fs[r] * acc[of][lf][r] + ba[r];
        }
    }
}

extern "C" void kernel_launch(void* const* d_in, const int* in_sizes, int n_in,
                              void* d_out, int out_size, void* d_ws, size_t ws_size,
                              hipStream_t stream) {
    const float* x           = (const float*)d_in[0];
    const float* conv_weight = (const float*)d_in[1];
    const float* bias_param  = (const float*)d_in[2];
    const float* grads       = (const float*)d_in[3];
    const float* W           = (const float*)d_in[4];
    const float* ctrl_w      = (const float*)d_in[5];
    const float* ctrl_b      = (const float*)d_in[6];
    const float* cw_w        = (const float*)d_in[7];
    const float* cw_b        = (const float*)d_in[8];
    const float* cb_w        = (const float*)d_in[9];
    const float* cb_b        = (const float*)d_in[10];
    const float* cf_w        = (const float*)d_in[11];
    const float* cf_b        = (const float*)d_in[12];
    const int*   trigger     = (const int*)d_in[13];

    float* out   = (float*)d_out;
    float* W_out = out + (size_t)32 * 128 * 4096;   // 16777216
    float* ws    = (float*)d_ws;
    _Float16* wfp = (_Float16*)(ws + WS_WF16);
    float* fsc   = ws + WS_FSC;
    float* badd  = ws + WS_BADD;

    k1_rep<<<257, 256, 0, stream>>>(grads, ctrl_w, ctrl_b, W, ws);
    k23<<<152, 256, 0, stream>>>(W, bias_param, conv_weight,
                                 cw_w, cw_b, cb_w, cb_b, cf_w, cf_b,
                                 trigger, ws, W_out, wfp);
    conv_mfma<<<2048, 256, 0, stream>>>(x, wfp, fsc, badd, out);
}

// Round 6
// 42.653 us; speedup vs baseline: 1.4482x; 1.4482x over previous
//
#include <hip/hip_runtime.h>
#include <hip/hip_bf16.h>
#include <math.h>

#define TAU 0.75f

typedef _Float16 half8 __attribute__((ext_vector_type(8)));
typedef float    f32x4 __attribute__((ext_vector_type(4)));

// ws layout (float offsets)
#define WS_Q     0      // q[448]
#define WS_NORM2 448    // base ||W||^2
#define WS_SCALE 449    // 1/norm
#define WS_V01   450    // v0, v1
#define WS_I01   452    // i0, i1 (ints)
#define WS_WQ    456    // blended w-scales [192]
#define WS_FSC   648    // f scale [128]
#define WS_BADD  776    // f*bias*b [128]
#define WS_OW    904    // old_w [448]
#define WS_WF16  1352   // f16 fused conv weights [3][128][64] (16B aligned)

// ---------------------------------------------------------------------------
// K1: blocks 0..63 -> chunk c: rep row + 7 q entries. block 64 -> ||W||^2.
// ---------------------------------------------------------------------------
__global__ __launch_bounds__(256) void k1_rep_q(
    const float* __restrict__ grads, const float* __restrict__ ctrl_w,
    const float* __restrict__ ctrl_b,
    const float* __restrict__ cw_w, const float* __restrict__ cw_b,
    const float* __restrict__ cb_w, const float* __restrict__ cb_b,
    const float* __restrict__ cf_w, const float* __restrict__ cf_b,
    const float* __restrict__ W, float* __restrict__ ws)
{
    const int t = threadIdx.x;
    if (blockIdx.x == 64) {
        __shared__ float red[256];
        float ss = 0.f;
        for (int e = t; e < 3584; e += 256) {
            const float4 w4 = ((const float4*)W)[e];
            ss += w4.x * w4.x + w4.y * w4.y + w4.z * w4.z + w4.w * w4.w;
        }
        red[t] = ss; __syncthreads();
        for (int s = 128; s > 0; s >>= 1) { if (t < s) red[t] += red[t + s]; __syncthreads(); }
        if (t == 0) ws[WS_NORM2] = red[0];
        return;
    }
    const int c = blockIdx.x;
    __shared__ float gS[384];
    __shared__ float repS[64];
    if (t < 96) ((float4*)gS)[t] = ((const float4*)(grads + c * 384))[t];
    __syncthreads();
    {
        const int h = t >> 2, sub = t & 3;
        const float4* wa = (const float4*)(ctrl_w + h * 384) + sub * 24;
        const float4* ga = (const float4*)gS + sub * 24;
        float dot = 0.f;
        #pragma unroll
        for (int d = 0; d < 24; d++) {
            const float4 a = ga[d], b = wa[d];
            dot += a.x * b.x + a.y * b.y + a.z * b.z + a.w * b.w;
        }
        dot += __shfl_xor(dot, 1);
        dot += __shfl_xor(dot, 2);
        if (sub == 0) {
            const float z = dot + ctrl_b[h];
            repS[h] = z / (1.f + expf(-z));
        }
    }
    __syncthreads();
    if (t < 7) {
        const float* wv; float bias; int e;
        if (t < 3)      { wv = cw_w + t * 64;       bias = cw_b[t];     e = 3 * c + t; }
        else if (t < 5) { const int j = t - 3; wv = cb_w + j * 64; bias = cb_b[j]; e = 192 + 2 * c + j; }
        else            { const int j = t - 5; wv = cf_w + j * 64; bias = cf_b[j]; e = 320 + 2 * c + j; }
        float dot = 0.f;
        #pragma unroll 8
        for (int h = 0; h < 64; h++) dot += repS[h] * wv[h];
        ws[WS_Q + e] = dot + bias;
    }
}

// ---------------------------------------------------------------------------
// K2: single block. Coalesced scores -> softmax/top2 -> fused old_w + norm
// correction -> scale -> blended scales (wq, fsc, badd) -> ws.
// ---------------------------------------------------------------------------
__global__ __launch_bounds__(256) void k2_small(
    const float* __restrict__ W, const float* __restrict__ bias_param,
    const int* __restrict__ trigger, float* __restrict__ ws)
{
    __shared__ float qS[448], owS[448], sS[32], sW[4][32], red[256];
    __shared__ int   idxS[2];
    __shared__ float vS[2];
    const int t = threadIdx.x;
    const int wv = t >> 6, lane = t & 63;
    const int trig = trigger[0];

    for (int e = t; e < 448; e += 256) qS[e] = ws[WS_Q + e];
    __syncthreads();

    // scores: coalesced — wave wv covers rows [wv*112, +112), lane: m=lane&31
    {
        const int m = lane & 31, half = lane >> 5;
        float s = 0.f;
        const int base = wv * 112;
        #pragma unroll 4
        for (int it = 0; it < 56; it++) {
            const int d = base + it * 2 + half;
            s += qS[d] * W[d * 32 + m];
        }
        s += __shfl_xor(s, 32);
        if (lane < 32) sW[wv][lane] = s;
    }
    __syncthreads();
    if (t < 32) sS[t] = 2.f * (sW[0][t] + sW[1][t] + sW[2][t] + sW[3][t]);
    __syncthreads();
    if (t == 0) {
        float mx = sS[0];
        for (int m = 1; m < 32; m++) mx = fmaxf(mx, sS[m]);
        float sum = 0.f; float att[32];
        for (int m = 0; m < 32; m++) { att[m] = expf(sS[m] - mx); sum += att[m]; }
        const float inv = 1.f / sum;
        int i0 = 0; float v0 = att[0];
        for (int m = 1; m < 32; m++) if (att[m] > v0) { v0 = att[m]; i0 = m; }
        int i1 = -1; float v1 = -1.f;
        for (int m = 0; m < 32; m++) { if (m == i0) continue; if (att[m] > v1) { v1 = att[m]; i1 = m; } }
        idxS[0] = i0; idxS[1] = i1; vS[0] = v0 * inv; vS[1] = v1 * inv;
    }
    __syncthreads();
    const int i0 = idxS[0], i1 = idxS[1];
    const float v0 = vS[0], v1 = vS[1];

    // fused old_w + norm correction
    float corr = 0.f;
    for (int d = t; d < 448; d += 256) {
        const float w0 = W[d * 32 + i0], w1 = W[d * 32 + i1];
        const float ow = (trig == 1) ? (w0 * (float)i0 + w1 * (float)i1) : 0.f;
        owS[d] = ow;
        if (trig == 1) {
            const float n0 = TAU * w0 + 0.25f * ow * v0;
            const float n1 = TAU * w1 + 0.25f * ow * v1;
            corr += n0 * n0 - w0 * w0 + n1 * n1 - w1 * w1;
        }
    }
    red[t] = corr; __syncthreads();
    for (int s = 128; s > 0; s >>= 1) { if (t < s) red[t] += red[t + s]; __syncthreads(); }
    if (t == 0) {
        const float n = sqrtf(fmaxf(ws[WS_NORM2] + red[0], 0.f));
        ws[WS_SCALE] = 1.f / fmaxf(n, 1.f);
        ws[WS_V01] = v0; ws[WS_V01 + 1] = v1;
        ((int*)ws)[WS_I01] = i0; ((int*)ws)[WS_I01 + 1] = i1;
    }

    if (t < 192) ws[WS_WQ + t] = (trig == 1) ? (TAU * qS[t] + 0.25f * owS[t]) : qS[t];
    if (t >= 64 && t < 192) {
        const int o = t - 64;
        // placeholder to keep lanes busy; real fsc/badd below
    }
    for (int o = t; o < 128; o += 256) {
        float bb = qS[192 + o], ff = qS[320 + o];
        if (trig == 1) {
            bb = TAU * bb + 0.25f * owS[192 + o];
            ff = TAU * ff + 0.25f * owS[320 + o];
        }
        ws[WS_FSC + o]  = ff;
        ws[WS_BADD + o] = ff * bias_param[o] * bb;
    }
    for (int d = t; d < 448; d += 256) ws[WS_OW + d] = owS[d];
}

// ---------------------------------------------------------------------------
// K3: 152 blocks: W_out[14336] + wf16[24576] from ws decisions.
// ---------------------------------------------------------------------------
__global__ __launch_bounds__(256) void k3_finalize(
    const float* __restrict__ W, const float* __restrict__ conv_weight,
    const int* __restrict__ trigger, const float* __restrict__ ws,
    float* __restrict__ W_out, _Float16* __restrict__ wf_out)
{
    const int g = blockIdx.x * 256 + threadIdx.x;
    const int trig = trigger[0];
    if (g < 14336) {
        const float wv = W[g];
        float wn = wv;
        if (trig == 1) {
            const int d = g >> 5, m = g & 31;
            const int i0 = ((const int*)ws)[WS_I01], i1 = ((const int*)ws)[WS_I01 + 1];
            if (m == i0)      wn = TAU * wv + 0.25f * ws[WS_OW + d] * ws[WS_V01];
            else if (m == i1) wn = TAU * wv + 0.25f * ws[WS_OW + d] * ws[WS_V01 + 1];
            wn *= ws[WS_SCALE];
        }
        W_out[g] = wn;
    } else {
        const int e2 = g - 14336;            // (o*64+i)*3+kk
        const int o   = e2 / 192;
        const int rem = e2 - o * 192;
        const int i   = rem / 3;
        const int kk  = rem - i * 3;
        wf_out[(kk * 128 + o) * 64 + i] = (_Float16)(conv_weight[e2] * ws[WS_WQ + rem]);
    }
}

// ---------------------------------------------------------------------------
// Conv via f16 MFMA. Block: 128 o x (2 x 64 l), double-buffered LDS.
// A-fragments loaded once per block; tile1 global loads issued before tile0
// compute (overlap via vmcnt); tile0 stores overlap tile1 ds_writes.
// Grid: 32 b * 32 l-groups = 1024 blocks (4/CU).
// ---------------------------------------------------------------------------
__global__ __launch_bounds__(256, 4) void conv_mfma(
    const float* __restrict__ x, const _Float16* __restrict__ wf,
    const float* __restrict__ fsc, const float* __restrict__ badd,
    float* __restrict__ out)
{
    __shared__ __align__(16) _Float16 xs[2][66 * 72];

    const int t    = threadIdx.x;
    const int wv   = t >> 6;
    const int lane = t & 63;
    const int lrow = lane & 15;
    const int lgrp = lane >> 4;
    const int b    = blockIdx.x >> 5;
    const int l0   = (blockIdx.x & 31) * 128;
    const int obase = wv * 32;

    const float* xb = x + (size_t)b * 64 * 4096;
    const int ci = t & 3;          // l-chunk of 16 within tile
    const int ir = t >> 2;         // row i, 0..63
    const int ei = t & 63;
    const int side = (t >> 6) & 1; // valid when t<128

    // A fragments: wf[kk][o][i]
    half8 A[2][2][3];
    #pragma unroll
    for (int of = 0; of < 2; of++)
        #pragma unroll
        for (int ch = 0; ch < 2; ch++)
            #pragma unroll
            for (int kk = 0; kk < 3; kk++)
                A[of][ch][kk] = *(const half8*)(wf + ((kk * 128 + obase + of * 16 + lrow) * 64 + ch * 32 + lgrp * 8));

    float4 xr0[4]; float xe0 = 0.f;
    float4 xr1[4]; float xe1 = 0.f;

    // ---- load tile0
    {
        const int lb = l0;
        #pragma unroll
        for (int j = 0; j < 4; j++)
            xr0[j] = *(const float4*)(xb + (size_t)ir * 4096 + lb + ci * 16 + j * 4);
        if (t < 128) {
            const int l = side ? (lb + 64) : (lb - 1);
            if (l >= 0 && l < 4096) xe0 = xb[(size_t)ei * 4096 + l];
        }
    }
    // ---- write tile0 to LDS
    {
        _Float16* buf = xs[0];
        #pragma unroll
        for (int j = 0; j < 4; j++) {
            _Float16* p = buf + (ci * 16 + j * 4 + 1) * 72 + ir;
            p[0]   = (_Float16)xr0[j].x;
            p[72]  = (_Float16)xr0[j].y;
            p[144] = (_Float16)xr0[j].z;
            p[216] = (_Float16)xr0[j].w;
        }
        if (t < 128) buf[(side ? 65 : 0) * 72 + ei] = (_Float16)xe0;
    }
    // ---- issue tile1 loads (in flight during tile0 compute)
    {
        const int lb = l0 + 64;
        #pragma unroll
        for (int j = 0; j < 4; j++)
            xr1[j] = *(const float4*)(xb + (size_t)ir * 4096 + lb + ci * 16 + j * 4);
        if (t < 128) {
            const int l = side ? (lb + 64) : (lb - 1);
            if (l >= 0 && l < 4096) xe1 = xb[(size_t)ei * 4096 + l];
        }
    }
    __syncthreads();   // buf0 ready

    #pragma unroll
    for (int tile = 0; tile < 2; tile++) {
        const _Float16* buf = xs[tile];
        const int lb = l0 + tile * 64;

        f32x4 acc[2][4];
        #pragma unroll
        for (int of = 0; of < 2; of++)
            #pragma unroll
            for (int lf = 0; lf < 4; lf++) acc[of][lf] = (f32x4)0.f;

        #pragma unroll
        for (int ch = 0; ch < 2; ch++) {
            #pragma unroll
            for (int kk = 0; kk < 3; kk++) {
                half8 B[4];
                #pragma unroll
                for (int lf = 0; lf < 4; lf++)
                    B[lf] = *(const half8*)(buf + (lf * 16 + lrow + kk) * 72 + ch * 32 + lgrp * 8);
                #pragma unroll
                for (int of = 0; of < 2; of++)
                    #pragma unroll
                    for (int lf = 0; lf < 4; lf++)
                        acc[of][lf] = __builtin_amdgcn_mfma_f32_16x16x32_f16(A[of][ch][kk], B[lf], acc[of][lf], 0, 0, 0);
            }
        }

        // epilogue: o = obase + of*16 + lgrp*4 + r ; l = lb + lf*16 + lrow
        #pragma unroll
        for (int of = 0; of < 2; of++) {
            const int ob = obase + of * 16 + lgrp * 4;
            float fs[4], ba[4];
            #pragma unroll
            for (int r = 0; r < 4; r++) { fs[r] = fsc[ob + r]; ba[r] = badd[ob + r]; }
            #pragma unroll
            for (int lf = 0; lf < 4; lf++) {
                const int l = lb + lf * 16 + lrow;
                float* op = out + ((size_t)(b * 128 + ob)) * 4096 + l;
                #pragma unroll
                for (int r = 0; r < 4; r++)
                    op[(size_t)r * 4096] = fs[r] * acc[of][lf][r] + ba[r];
            }
        }

        if (tile == 0) {
            // write tile1 to LDS (waits on its global loads via vmcnt)
            _Float16* buf1 = xs[1];
            #pragma unroll
            for (int j = 0; j < 4; j++) {
                _Float16* p = buf1 + (ci * 16 + j * 4 + 1) * 72 + ir;
                p[0]   = (_Float16)xr1[j].x;
                p[72]  = (_Float16)xr1[j].y;
                p[144] = (_Float16)xr1[j].z;
                p[216] = (_Float16)xr1[j].w;
            }
            if (t < 128) buf1[(side ? 65 : 0) * 72 + ei] = (_Float16)xe1;
            __syncthreads();   // buf1 ready
        }
    }
}

extern "C" void kernel_launch(void* const* d_in, const int* in_sizes, int n_in,
                              void* d_out, int out_size, void* d_ws, size_t ws_size,
                              hipStream_t stream) {
    const float* x           = (const float*)d_in[0];
    const float* conv_weight = (const float*)d_in[1];
    const float* bias_param  = (const float*)d_in[2];
    const float* grads       = (const float*)d_in[3];
    const float* W           = (const float*)d_in[4];
    const float* ctrl_w      = (const float*)d_in[5];
    const float* ctrl_b      = (const float*)d_in[6];
    const float* cw_w        = (const float*)d_in[7];
    const float* cw_b        = (const float*)d_in[8];
    const float* cb_w        = (const float*)d_in[9];
    const float* cb_b        = (const float*)d_in[10];
    const float* cf_w        = (const float*)d_in[11];
    const float* cf_b        = (const float*)d_in[12];
    const int*   trigger     = (const int*)d_in[13];

    float* out   = (float*)d_out;
    float* W_out = out + (size_t)32 * 128 * 4096;   // 16777216
    float* ws    = (float*)d_ws;
    _Float16* wfp = (_Float16*)(ws + WS_WF16);
    float* fsc   = ws + WS_FSC;
    float* badd  = ws + WS_BADD;

    k1_rep_q<<<65, 256, 0, stream>>>(grads, ctrl_w, ctrl_b, cw_w, cw_b,
                                     cb_w, cb_b, cf_w, cf_b, W, ws);
    k2_small<<<1, 256, 0, stream>>>(W, bias_param, trigger, ws);
    k3_finalize<<<152, 256, 0, stream>>>(W, conv_weight, trigger, ws, W_out, wfp);
    conv_mfma<<<1024, 256, 0, stream>>>(x, wfp, fsc, badd, out);
}